// Round 1
// baseline (5813.405 us; speedup 1.0000x reference)
//
#include <hip/hip_runtime.h>

#define IN_CH 11
#define EDGE_CH 22
#define HID 64
#define N_CLS 2
#define N_GRAPHS 256

// ---------------------------------------------------------------------------
// Edge kernel: ec = edge_attr @ we.T + be, scatter-add to x0[src]; deg[dst]+=1
// ---------------------------------------------------------------------------
__global__ void edge_kernel(const float* __restrict__ ea,
                            const int* __restrict__ src,
                            const int* __restrict__ dst,
                            const float* __restrict__ we,
                            const float* __restrict__ be,
                            float* __restrict__ x0,
                            float* __restrict__ deg,
                            int E) {
    __shared__ float s_we[IN_CH * EDGE_CH];
    __shared__ float s_be[IN_CH];
    for (int i = threadIdx.x; i < IN_CH * EDGE_CH; i += blockDim.x) s_we[i] = we[i];
    if (threadIdx.x < IN_CH) s_be[threadIdx.x] = be[threadIdx.x];
    __syncthreads();

    int t = blockIdx.x * blockDim.x + threadIdx.x;
    int stride = gridDim.x * blockDim.x;
    for (int e = t; e < E; e += stride) {
        float a[EDGE_CH];
#pragma unroll
        for (int k = 0; k < EDGE_CH; ++k) a[k] = ea[(long)e * EDGE_CH + k];
        int s = src[e];
#pragma unroll
        for (int o = 0; o < IN_CH; ++o) {
            float acc = s_be[o];
#pragma unroll
            for (int k = 0; k < EDGE_CH; ++k) acc += a[k] * s_we[o * EDGE_CH + k];
            atomicAdd(&x0[(long)s * IN_CH + o], acc);
        }
        atomicAdd(&deg[dst[e]], 1.0f);
    }
}

// ---------------------------------------------------------------------------
// Aggregation, C=11: thread per edge
// ---------------------------------------------------------------------------
__global__ void agg11_kernel(const float* __restrict__ h,
                             const int* __restrict__ src,
                             const int* __restrict__ dst,
                             float* __restrict__ agg,
                             int E) {
    int t = blockIdx.x * blockDim.x + threadIdx.x;
    int stride = gridDim.x * blockDim.x;
    for (int e = t; e < E; e += stride) {
        int s = src[e], d = dst[e];
#pragma unroll
        for (int c = 0; c < IN_CH; ++c) {
            atomicAdd(&agg[(long)d * IN_CH + c], h[(long)s * IN_CH + c]);
        }
    }
}

// ---------------------------------------------------------------------------
// Aggregation, C=64: one wave (64 lanes) per edge, lane = channel
// ---------------------------------------------------------------------------
__global__ void agg64_kernel(const float* __restrict__ h,
                             const int* __restrict__ src,
                             const int* __restrict__ dst,
                             float* __restrict__ agg,
                             int E) {
    int lane = threadIdx.x & 63;
    int wave = (blockIdx.x * blockDim.x + threadIdx.x) >> 6;
    int nwaves = (gridDim.x * blockDim.x) >> 6;
    for (int e = wave; e < E; e += nwaves) {
        int s = src[e], d = dst[e];
        float v = h[(long)s * HID + lane];
        atomicAdd(&agg[(long)d * HID + lane], v);
    }
}

// ---------------------------------------------------------------------------
// Node update: h_out[n] = relu(mean(n) @ lw.T + lb + h_in[n] @ rw.T)
// 4 nodes per block (64 lanes each, lane = out channel). Weights staged in
// LDS transposed so lane-o access s_lw[c][o] is 2-way-bank (free on gfx950).
// Safe for h_out aliasing agg (row read into LDS before row write).
// ---------------------------------------------------------------------------
template <int CIN>
__global__ void update_kernel(const float* __restrict__ h_in,
                              const float* __restrict__ agg,
                              const float* __restrict__ deg,
                              const float* __restrict__ lw,
                              const float* __restrict__ lb,
                              const float* __restrict__ rw,
                              float* __restrict__ h_out,
                              int N) {
    __shared__ float s_lw[CIN][HID];   // transposed [c][o]
    __shared__ float s_rw[CIN][HID];
    __shared__ float s_lb[HID];
    __shared__ float s_hin[4][CIN];
    __shared__ float s_mean[4][CIN];

    for (int i = threadIdx.x; i < HID * CIN; i += blockDim.x) {
        int o = i / CIN, c = i % CIN;
        s_lw[c][o] = lw[i];
        s_rw[c][o] = rw[i];
    }
    if (threadIdx.x < HID) s_lb[threadIdx.x] = lb[threadIdx.x];
    __syncthreads();

    int sub = threadIdx.x >> 6;
    int lane = threadIdx.x & 63;
    int groups = (N + 3) >> 2;
    for (int g = blockIdx.x; g < groups; g += gridDim.x) {
        int n = g * 4 + sub;
        bool valid = n < N;
        if (valid && lane < CIN) {
            s_hin[sub][lane] = h_in[(long)n * CIN + lane];
            float dg = deg[n];
            float inv = 1.0f / fmaxf(dg, 1.0f);
            s_mean[sub][lane] = agg[(long)n * CIN + lane] * inv;
        }
        __syncthreads();
        if (valid) {
            float acc = s_lb[lane];
#pragma unroll
            for (int c = 0; c < CIN; ++c)
                acc += s_mean[sub][c] * s_lw[c][lane] + s_hin[sub][c] * s_rw[c][lane];
            h_out[(long)n * HID + lane] = fmaxf(acc, 0.0f);
        }
        __syncthreads();
    }
}

// ---------------------------------------------------------------------------
// Pooling: batch is sorted; per-block running segmented sums, flush on graph
// change. One wave per block, lane = channel.
// ---------------------------------------------------------------------------
__global__ void pool_kernel(const float* __restrict__ h,
                            const int* __restrict__ batch,
                            float* __restrict__ psum,
                            float* __restrict__ pcnt,
                            int N, int chunk) {
    int lane = threadIdx.x;  // blockDim.x == 64
    int n0 = blockIdx.x * chunk;
    int n1 = min(n0 + chunk, N);
    float acc = 0.0f, cnt = 0.0f;
    int cur = -1;
    for (int n = n0; n < n1; ++n) {
        int g = batch[n];
        if (g != cur) {
            if (cur >= 0) {
                atomicAdd(&psum[(long)cur * HID + lane], acc);
                if (lane == 0) atomicAdd(&pcnt[cur], cnt);
            }
            cur = g;
            acc = 0.0f;
            cnt = 0.0f;
        }
        acc += h[(long)n * HID + lane];
        cnt += 1.0f;
    }
    if (cur >= 0) {
        atomicAdd(&psum[(long)cur * HID + lane], acc);
        if (lane == 0) atomicAdd(&pcnt[cur], cnt);
    }
}

// ---------------------------------------------------------------------------
// Final classifier: out[g,k] = (psum[g]/max(cnt,1)) . wf[k] + bf[k]
// ---------------------------------------------------------------------------
__global__ void final_kernel(const float* __restrict__ psum,
                             const float* __restrict__ pcnt,
                             const float* __restrict__ wf,
                             const float* __restrict__ bf,
                             float* __restrict__ out,
                             int G) {
    int g = blockIdx.x * blockDim.x + threadIdx.x;
    if (g < G) {
        float inv = 1.0f / fmaxf(pcnt[g], 1.0f);
        float o0 = bf[0], o1 = bf[1];
#pragma unroll
        for (int c = 0; c < HID; ++c) {
            float p = psum[(long)g * HID + c] * inv;
            o0 += p * wf[c];
            o1 += p * wf[HID + c];
        }
        out[g * N_CLS + 0] = o0;
        out[g * N_CLS + 1] = o1;
    }
}

extern "C" void kernel_launch(void* const* d_in, const int* in_sizes, int n_in,
                              void* d_out, int out_size, void* d_ws, size_t ws_size,
                              hipStream_t stream) {
    const float* x         = (const float*)d_in[0];
    const float* edge_attr = (const float*)d_in[1];
    const int*   edge_idx  = (const int*)d_in[2];
    const int*   batch     = (const int*)d_in[3];
    const float* we  = (const float*)d_in[4];
    const float* be  = (const float*)d_in[5];
    const float* l1w = (const float*)d_in[6];
    const float* l1b = (const float*)d_in[7];
    const float* r1w = (const float*)d_in[8];
    const float* l2w = (const float*)d_in[9];
    const float* l2b = (const float*)d_in[10];
    const float* r2w = (const float*)d_in[11];
    const float* l3w = (const float*)d_in[12];
    const float* l3b = (const float*)d_in[13];
    const float* r3w = (const float*)d_in[14];
    const float* wf  = (const float*)d_in[15];
    const float* bf  = (const float*)d_in[16];

    const int E = in_sizes[2] / 2;
    const int N = in_sizes[3];
    const int* src = edge_idx;
    const int* dst = edge_idx + E;

    // Workspace layout (floats)
    float* ws   = (float*)d_ws;
    float* x0   = ws;                      // N*11
    float* deg  = x0 + (size_t)N * IN_CH;  // N
    float* bufA = deg + N;                 // N*64
    float* bufB = bufA + (size_t)N * HID;  // N*64
    float* psum = bufB + (size_t)N * HID;  // 256*64
    float* pcnt = psum + N_GRAPHS * HID;   // 256

    // 1) x0 = x ; zero accumulators
    hipMemcpyAsync(x0, x, (size_t)N * IN_CH * sizeof(float),
                   hipMemcpyDeviceToDevice, stream);
    hipMemsetAsync(deg, 0, (size_t)N * sizeof(float), stream);
    hipMemsetAsync(bufA, 0, (size_t)N * IN_CH * sizeof(float), stream);

    // 2) edge correction + degree
    edge_kernel<<<2048, 256, 0, stream>>>(edge_attr, src, dst, we, be, x0, deg, E);

    // 3) layer 1: agg (11ch) -> update -> bufB
    agg11_kernel<<<2048, 256, 0, stream>>>(x0, src, dst, bufA, E);
    update_kernel<IN_CH><<<2048, 256, 0, stream>>>(x0, bufA, deg, l1w, l1b, r1w, bufB, N);

    // 4) layer 2: agg (64ch) into bufA -> update in-place into bufA
    hipMemsetAsync(bufA, 0, (size_t)N * HID * sizeof(float), stream);
    agg64_kernel<<<4096, 256, 0, stream>>>(bufB, src, dst, bufA, E);
    update_kernel<HID><<<2048, 256, 0, stream>>>(bufB, bufA, deg, l2w, l2b, r2w, bufA, N);

    // 5) layer 3: agg into bufB -> update in-place into bufB
    hipMemsetAsync(bufB, 0, (size_t)N * HID * sizeof(float), stream);
    agg64_kernel<<<4096, 256, 0, stream>>>(bufA, src, dst, bufB, E);
    update_kernel<HID><<<2048, 256, 0, stream>>>(bufA, bufB, deg, l3w, l3b, r3w, bufB, N);

    // 6) pool + classify
    hipMemsetAsync(psum, 0, (size_t)(N_GRAPHS * HID + N_GRAPHS) * sizeof(float), stream);
    {
        int pb = 256;
        int chunk = (N + pb - 1) / pb;
        pool_kernel<<<pb, 64, 0, stream>>>(bufB, batch, psum, pcnt, N, chunk);
    }
    final_kernel<<<(N_GRAPHS + 255) / 256, 256, 0, stream>>>(psum, pcnt, wf, bf,
                                                             (float*)d_out, N_GRAPHS);
}

// Round 2
// 2382.840 us; speedup vs baseline: 2.4397x; 2.4397x over previous
//
#include <hip/hip_runtime.h>

#define IN_CH 11
#define EDGE_CH 22
#define HID 64
#define N_CLS 2
#define N_GRAPHS 256

// ---------------------------------------------------------------------------
// CSR build step 1: per-node edge counts (src and dst)
// ---------------------------------------------------------------------------
__global__ void hist_kernel(const int* __restrict__ src, const int* __restrict__ dst,
                            int* __restrict__ cnt_src, int* __restrict__ cnt_dst, int E) {
    int e = blockIdx.x * blockDim.x + threadIdx.x;
    if (e < E) {
        atomicAdd(&cnt_src[src[e]], 1);
        atomicAdd(&cnt_dst[dst[e]], 1);
    }
}

// ---------------------------------------------------------------------------
// CSR build step 2: exclusive prefix scan. grid=2 (block 0: src, block 1: dst),
// 1024 threads; each thread serial-sums a contiguous chunk, block-scan in LDS,
// then re-walk writing exclusive offsets. off[N] = total.
// ---------------------------------------------------------------------------
__global__ void scan_kernel(const int* __restrict__ cnt_src, int* __restrict__ off_src,
                            const int* __restrict__ cnt_dst, int* __restrict__ off_dst,
                            int N) {
    const int* cnt = (blockIdx.x == 0) ? cnt_src : cnt_dst;
    int* off = (blockIdx.x == 0) ? off_src : off_dst;
    __shared__ int lds[1024];
    int t = threadIdx.x;
    int chunk = (N + 1023) >> 10;
    int lo = t * chunk, hi = min(N, lo + chunk);
    int s = 0;
    for (int i = lo; i < hi; ++i) s += cnt[i];
    lds[t] = s;
    __syncthreads();
    for (int d = 1; d < 1024; d <<= 1) {
        int v = (t >= d) ? lds[t - d] : 0;
        __syncthreads();
        lds[t] += v;
        __syncthreads();
    }
    int base = (t > 0) ? lds[t - 1] : 0;
    for (int i = lo; i < hi; ++i) { off[i] = base; base += cnt[i]; }
    if (t == 0) off[N] = lds[1023];
}

// ---------------------------------------------------------------------------
// CSR build step 3: fill edge lists. src-CSR stores edge id (to index
// edge_attr); dst-CSR stores the source node id directly (skips indirection).
// ---------------------------------------------------------------------------
__global__ void fill_kernel(const int* __restrict__ src, const int* __restrict__ dst,
                            int* __restrict__ cur_src, int* __restrict__ cur_dst,
                            int* __restrict__ src_edge, int* __restrict__ dst_srcid,
                            int E) {
    int e = blockIdx.x * blockDim.x + threadIdx.x;
    if (e < E) {
        int s = src[e], d = dst[e];
        int p = atomicAdd(&cur_src[s], 1);
        src_edge[p] = e;
        int q = atomicAdd(&cur_dst[d], 1);
        dst_srcid[q] = s;
    }
}

// ---------------------------------------------------------------------------
// agg_ea[n] = sum over out-edges of edge_attr[e]  (wave per node; lanes split
// into 2 groups of 22 channels handling edges i, i+1; cross-add via shfl)
// ---------------------------------------------------------------------------
__global__ void ea_gather_kernel(const float* __restrict__ ea,
                                 const int* __restrict__ off_src,
                                 const int* __restrict__ src_edge,
                                 float* __restrict__ agg_ea, int N) {
    int wave = (blockIdx.x * blockDim.x + threadIdx.x) >> 6;
    int lane = threadIdx.x & 63;
    if (wave >= N) return;
    int beg = off_src[wave], end = off_src[wave + 1];
    int j = lane >> 5;    // 0/1 : which edge of the pair
    int c = lane & 31;    // channel
    float acc = 0.0f;
    if (c < EDGE_CH) {
        for (int i = beg + j; i < end; i += 2) {
            int e = src_edge[i];
            acc += ea[(long)e * EDGE_CH + c];
        }
    }
    acc += __shfl_xor(acc, 32, 64);
    if (lane < EDGE_CH) agg_ea[(long)wave * EDGE_CH + lane] = acc;
}

// ---------------------------------------------------------------------------
// x0[n] = x[n] + agg_ea[n] @ we.T + outdeg(n) * be    (thread per node)
// ---------------------------------------------------------------------------
__global__ void x0_update_kernel(const float* __restrict__ x,
                                 const float* __restrict__ agg_ea,
                                 const int* __restrict__ off_src,
                                 const float* __restrict__ we,
                                 const float* __restrict__ be,
                                 float* __restrict__ x0, int N) {
    __shared__ float s_we[IN_CH * EDGE_CH];
    __shared__ float s_be[IN_CH];
    for (int i = threadIdx.x; i < IN_CH * EDGE_CH; i += blockDim.x) s_we[i] = we[i];
    if (threadIdx.x < IN_CH) s_be[threadIdx.x] = be[threadIdx.x];
    __syncthreads();
    int n = blockIdx.x * blockDim.x + threadIdx.x;
    if (n >= N) return;
    float a[EDGE_CH];
#pragma unroll
    for (int k = 0; k < EDGE_CH; ++k) a[k] = agg_ea[(long)n * EDGE_CH + k];
    float cnt = (float)(off_src[n + 1] - off_src[n]);
#pragma unroll
    for (int o = 0; o < IN_CH; ++o) {
        float acc = x[(long)n * IN_CH + o] + cnt * s_be[o];
#pragma unroll
        for (int k = 0; k < EDGE_CH; ++k) acc += a[k] * s_we[o * EDGE_CH + k];
        x0[(long)n * IN_CH + o] = acc;
    }
}

// ---------------------------------------------------------------------------
// mean11[n] = mean over in-edges of x0[srcid]  (wave per node; 4 groups of 16
// lanes, 11 channels active each, handling edges i..i+3; shfl reduce)
// ---------------------------------------------------------------------------
__global__ void agg11_kernel(const float* __restrict__ h,
                             const int* __restrict__ off_dst,
                             const int* __restrict__ srcid,
                             float* __restrict__ mean, int N) {
    int wave = (blockIdx.x * blockDim.x + threadIdx.x) >> 6;
    int lane = threadIdx.x & 63;
    if (wave >= N) return;
    int beg = off_dst[wave], end = off_dst[wave + 1];
    int j = lane >> 4;    // 0..3
    int c = lane & 15;
    float acc = 0.0f;
    if (c < IN_CH) {
        for (int i = beg + j; i < end; i += 4) {
            int s = srcid[i];
            acc += h[(long)s * IN_CH + c];
        }
    }
    acc += __shfl_xor(acc, 16, 64);
    acc += __shfl_xor(acc, 32, 64);
    if (lane < IN_CH) {
        float inv = 1.0f / fmaxf((float)(end - beg), 1.0f);
        mean[(long)wave * IN_CH + lane] = acc * inv;
    }
}

// ---------------------------------------------------------------------------
// mean64[n] = mean over in-edges of h[srcid]  (wave per node, lane = channel;
// 256 B coalesced row gathers, 2-way unrolled for MLP; no atomics)
// ---------------------------------------------------------------------------
__global__ void agg64_kernel(const float* __restrict__ h,
                             const int* __restrict__ off_dst,
                             const int* __restrict__ srcid,
                             float* __restrict__ mean, int N) {
    int wave = (blockIdx.x * blockDim.x + threadIdx.x) >> 6;
    int lane = threadIdx.x & 63;
    if (wave >= N) return;
    int beg = off_dst[wave], end = off_dst[wave + 1];
    float a0 = 0.0f, a1 = 0.0f;
    int i = beg;
    for (; i + 1 < end; i += 2) {
        int s0 = srcid[i], s1 = srcid[i + 1];
        a0 += h[(long)s0 * HID + lane];
        a1 += h[(long)s1 * HID + lane];
    }
    if (i < end) a0 += h[(long)srcid[i] * HID + lane];
    float inv = 1.0f / fmaxf((float)(end - beg), 1.0f);
    mean[(long)wave * HID + lane] = (a0 + a1) * inv;
}

// ---------------------------------------------------------------------------
// h_out[n] = relu(mean[n] @ lw.T + lb + h_in[n] @ rw.T)
// 4 nodes/block, lane = out channel, weights transposed in LDS.
// ---------------------------------------------------------------------------
template <int CIN>
__global__ void update_kernel(const float* __restrict__ h_in,
                              const float* __restrict__ mean,
                              const float* __restrict__ lw,
                              const float* __restrict__ lb,
                              const float* __restrict__ rw,
                              float* __restrict__ h_out, int N) {
    __shared__ float s_lw[CIN][HID];
    __shared__ float s_rw[CIN][HID];
    __shared__ float s_lb[HID];
    __shared__ float s_hin[4][CIN];
    __shared__ float s_mean[4][CIN];
    for (int i = threadIdx.x; i < HID * CIN; i += blockDim.x) {
        int o = i / CIN, c = i % CIN;
        s_lw[c][o] = lw[i];
        s_rw[c][o] = rw[i];
    }
    if (threadIdx.x < HID) s_lb[threadIdx.x] = lb[threadIdx.x];
    __syncthreads();
    int sub = threadIdx.x >> 6, lane = threadIdx.x & 63;
    int groups = (N + 3) >> 2;
    for (int g = blockIdx.x; g < groups; g += gridDim.x) {
        int n = g * 4 + sub;
        bool valid = n < N;
        if (valid && lane < CIN) {
            s_hin[sub][lane] = h_in[(long)n * CIN + lane];
            s_mean[sub][lane] = mean[(long)n * CIN + lane];
        }
        __syncthreads();
        if (valid) {
            float acc = s_lb[lane];
#pragma unroll
            for (int c2 = 0; c2 < CIN; ++c2)
                acc += s_mean[sub][c2] * s_lw[c2][lane] + s_hin[sub][c2] * s_rw[c2][lane];
            h_out[(long)n * HID + lane] = fmaxf(acc, 0.0f);
        }
        __syncthreads();
    }
}

// ---------------------------------------------------------------------------
// Pooling over sorted batch: per-block running segmented sums.
// ---------------------------------------------------------------------------
__global__ void pool_kernel(const float* __restrict__ h,
                            const int* __restrict__ batch,
                            float* __restrict__ psum,
                            float* __restrict__ pcnt,
                            int N, int chunk) {
    int lane = threadIdx.x;  // blockDim.x == 64
    int n0 = blockIdx.x * chunk;
    int n1 = min(n0 + chunk, N);
    float acc = 0.0f, cnt = 0.0f;
    int cur = -1;
    for (int n = n0; n < n1; ++n) {
        int g = batch[n];
        if (g != cur) {
            if (cur >= 0) {
                atomicAdd(&psum[(long)cur * HID + lane], acc);
                if (lane == 0) atomicAdd(&pcnt[cur], cnt);
            }
            cur = g;
            acc = 0.0f;
            cnt = 0.0f;
        }
        acc += h[(long)n * HID + lane];
        cnt += 1.0f;
    }
    if (cur >= 0) {
        atomicAdd(&psum[(long)cur * HID + lane], acc);
        if (lane == 0) atomicAdd(&pcnt[cur], cnt);
    }
}

__global__ void final_kernel(const float* __restrict__ psum,
                             const float* __restrict__ pcnt,
                             const float* __restrict__ wf,
                             const float* __restrict__ bf,
                             float* __restrict__ out, int G) {
    int g = blockIdx.x * blockDim.x + threadIdx.x;
    if (g < G) {
        float inv = 1.0f / fmaxf(pcnt[g], 1.0f);
        float o0 = bf[0], o1 = bf[1];
#pragma unroll
        for (int c = 0; c < HID; ++c) {
            float p = psum[(long)g * HID + c] * inv;
            o0 += p * wf[c];
            o1 += p * wf[HID + c];
        }
        out[g * N_CLS + 0] = o0;
        out[g * N_CLS + 1] = o1;
    }
}

extern "C" void kernel_launch(void* const* d_in, const int* in_sizes, int n_in,
                              void* d_out, int out_size, void* d_ws, size_t ws_size,
                              hipStream_t stream) {
    const float* x         = (const float*)d_in[0];
    const float* edge_attr = (const float*)d_in[1];
    const int*   edge_idx  = (const int*)d_in[2];
    const int*   batch     = (const int*)d_in[3];
    const float* we  = (const float*)d_in[4];
    const float* be  = (const float*)d_in[5];
    const float* l1w = (const float*)d_in[6];
    const float* l1b = (const float*)d_in[7];
    const float* r1w = (const float*)d_in[8];
    const float* l2w = (const float*)d_in[9];
    const float* l2b = (const float*)d_in[10];
    const float* r2w = (const float*)d_in[11];
    const float* l3w = (const float*)d_in[12];
    const float* l3b = (const float*)d_in[13];
    const float* r3w = (const float*)d_in[14];
    const float* wf  = (const float*)d_in[15];
    const float* bf  = (const float*)d_in[16];

    const int E = in_sizes[2] / 2;
    const int N = in_sizes[3];
    const int* src = edge_idx;
    const int* dst = edge_idx + E;

    // ---- workspace layout (all 4-byte typed) ----
    char* p = (char*)d_ws;
    int* off_src   = (int*)p;            p += (size_t)(N + 1) * 4;
    int* off_dst   = (int*)p;            p += (size_t)(N + 1) * 4;
    int* cur_src   = (int*)p;            p += (size_t)N * 4;   // also cnt_src
    int* cur_dst   = (int*)p;            p += (size_t)N * 4;   // also cnt_dst
    int* src_edge  = (int*)p;            p += (size_t)E * 4;
    int* dst_srcid = (int*)p;            p += (size_t)E * 4;
    float* x0      = (float*)p;          p += (size_t)N * IN_CH * 4;
    float* tmpM    = (float*)p;          p += (size_t)N * HID * 4;  // agg_ea/mean11/mean64 union
    float* bufA    = (float*)p;          p += (size_t)N * HID * 4;
    float* bufB    = (float*)p;          p += (size_t)N * HID * 4;
    float* psum    = (float*)p;          p += (size_t)N_GRAPHS * HID * 4;
    float* pcnt    = (float*)p;          p += (size_t)N_GRAPHS * 4;

    const int EB = (E + 255) / 256;       // edge-parallel blocks
    const int NW = (N + 3) / 4;           // wave-per-node blocks (256 thr = 4 waves)

    // ---- CSR build ----
    hipMemsetAsync(cur_src, 0, (size_t)N * 4, stream);
    hipMemsetAsync(cur_dst, 0, (size_t)N * 4, stream);
    hist_kernel<<<EB, 256, 0, stream>>>(src, dst, cur_src, cur_dst, E);
    scan_kernel<<<2, 1024, 0, stream>>>(cur_src, off_src, cur_dst, off_dst, N);
    hipMemcpyAsync(cur_src, off_src, (size_t)N * 4, hipMemcpyDeviceToDevice, stream);
    hipMemcpyAsync(cur_dst, off_dst, (size_t)N * 4, hipMemcpyDeviceToDevice, stream);
    fill_kernel<<<EB, 256, 0, stream>>>(src, dst, cur_src, cur_dst, src_edge, dst_srcid, E);

    // ---- edge correction (algebraic fold: segment-sum edge_attr, then GEMV) ----
    ea_gather_kernel<<<NW, 256, 0, stream>>>(edge_attr, off_src, src_edge, tmpM, N);
    x0_update_kernel<<<(N + 255) / 256, 256, 0, stream>>>(x, tmpM, off_src, we, be, x0, N);

    // ---- layer 1 ----
    agg11_kernel<<<NW, 256, 0, stream>>>(x0, off_dst, dst_srcid, tmpM, N);
    update_kernel<IN_CH><<<2048, 256, 0, stream>>>(x0, tmpM, l1w, l1b, r1w, bufA, N);

    // ---- layer 2 ----
    agg64_kernel<<<NW, 256, 0, stream>>>(bufA, off_dst, dst_srcid, tmpM, N);
    update_kernel<HID><<<2048, 256, 0, stream>>>(bufA, tmpM, l2w, l2b, r2w, bufB, N);

    // ---- layer 3 ----
    agg64_kernel<<<NW, 256, 0, stream>>>(bufB, off_dst, dst_srcid, tmpM, N);
    update_kernel<HID><<<2048, 256, 0, stream>>>(bufB, tmpM, l3w, l3b, r3w, bufA, N);

    // ---- pool + classify ----
    hipMemsetAsync(psum, 0, (size_t)(N_GRAPHS * HID + N_GRAPHS) * 4, stream);
    {
        int pb = 256;
        int chunk = (N + pb - 1) / pb;
        pool_kernel<<<pb, 64, 0, stream>>>(bufA, batch, psum, pcnt, N, chunk);
    }
    final_kernel<<<(N_GRAPHS + 255) / 256, 256, 0, stream>>>(psum, pcnt, wf, bf,
                                                             (float*)d_out, N_GRAPHS);
}

// Round 3
// 1508.073 us; speedup vs baseline: 3.8549x; 1.5801x over previous
//
#include <hip/hip_runtime.h>
#include <stdint.h>

#define IN_CH 11
#define EDGE_CH 22
#define HID 64
#define N_CLS 2
#define N_GRAPHS 256

// Coarse buckets: 256 nodes per bucket (node >> 8). N=100000 -> 391 buckets.
#define BK_SHIFT 8
#define BK_NODES 256
#define MAXBUK 512          // padded power-of-2 for scans
#define L1_CHUNK 4096       // edges per binscatter block
#define L2_CAP 16384        // LDS staging entries in bucket_csr (64 KB)

// src-side pack: (local<<22)|edge_id   (edge_id < 2^22 = 4.19M)
// dst-side pack: (local<<17)|src_id    (src_id  < 2^17 = 131072)
#define SRC_SHIFT 22
#define DST_SHIFT 17

// ---------------------------------------------------------------------------
// Step 1: coarse bucket histogram (LDS-staged, one flush per block)
// ---------------------------------------------------------------------------
__global__ void prehist_kernel(const int* __restrict__ src, const int* __restrict__ dst,
                               int* __restrict__ bc_src, int* __restrict__ bc_dst,
                               int E, int nbuk) {
    __shared__ int h_s[MAXBUK], h_d[MAXBUK];
    int t = threadIdx.x;  // 256
    for (int i = t; i < MAXBUK; i += 256) { h_s[i] = 0; h_d[i] = 0; }
    __syncthreads();
    int per = (E + gridDim.x - 1) / gridDim.x;
    int lo = blockIdx.x * per, hi = min(E, lo + per);
    for (int i = lo + t; i < hi; i += 256) {
        atomicAdd(&h_s[src[i] >> BK_SHIFT], 1);
        atomicAdd(&h_d[dst[i] >> BK_SHIFT], 1);
    }
    __syncthreads();
    for (int i = t; i < nbuk; i += 256) {
        if (h_s[i]) atomicAdd(&bc_src[i], h_s[i]);
        if (h_d[i]) atomicAdd(&bc_dst[i], h_d[i]);
    }
}

// ---------------------------------------------------------------------------
// Step 2: scan bucket counts -> bucket base offsets (+ cursor copies).
// Single block, 512 threads.
// ---------------------------------------------------------------------------
__global__ void bucket_scan_kernel(const int* __restrict__ bc_src, const int* __restrict__ bc_dst,
                                   int* __restrict__ boff_src, int* __restrict__ boff_dst,
                                   int* __restrict__ gcur_src, int* __restrict__ gcur_dst,
                                   int* __restrict__ off_src, int* __restrict__ off_dst,
                                   int nbuk, int N, int E) {
    __shared__ int a[MAXBUK], b[MAXBUK];
    int t = threadIdx.x;  // 512
    int ca = (t < nbuk) ? bc_src[t] : 0;
    int cb = (t < nbuk) ? bc_dst[t] : 0;
    a[t] = ca; b[t] = cb;
    __syncthreads();
    for (int d = 1; d < MAXBUK; d <<= 1) {
        int ua = (t >= d) ? a[t - d] : 0;
        int ub = (t >= d) ? b[t - d] : 0;
        __syncthreads();
        a[t] += ua; b[t] += ub;
        __syncthreads();
    }
    if (t < nbuk) {
        int ea = a[t] - ca, eb = b[t] - cb;
        boff_src[t] = ea; gcur_src[t] = ea;
        boff_dst[t] = eb; gcur_dst[t] = eb;
    }
    if (t == 0) {
        boff_src[nbuk] = E; boff_dst[nbuk] = E;
        off_src[N] = E; off_dst[N] = E;
    }
}

// ---------------------------------------------------------------------------
// Step 3: bin edges by coarse bucket, LDS-sorted per 4096-edge chunk, runs
// written out coalesced. 512 threads.
// ---------------------------------------------------------------------------
__global__ void binscatter_kernel(const int* __restrict__ src, const int* __restrict__ dst,
                                  int* __restrict__ gcur_src, int* __restrict__ gcur_dst,
                                  uint32_t* __restrict__ bin_src, uint32_t* __restrict__ bin_dst,
                                  int E, int nbuk) {
    __shared__ int h_s[MAXBUK], h_d[MAXBUK];
    __shared__ int off_s[MAXBUK], off_d[MAXBUK];
    __shared__ int cur_s[MAXBUK], cur_d[MAXBUK];
    __shared__ int base_s[MAXBUK], base_d[MAXBUK];
    __shared__ uint32_t st_s[L1_CHUNK], st_d[L1_CHUNK];
    __shared__ unsigned short bk_s[L1_CHUNK], bk_d[L1_CHUNK];

    int t = threadIdx.x;  // 512
    int e0 = blockIdx.x * L1_CHUNK;
    int ecnt = min(E - e0, L1_CHUNK);

    h_s[t] = 0; h_d[t] = 0;
    __syncthreads();
    for (int i = t; i < ecnt; i += 512) {
        atomicAdd(&h_s[src[e0 + i] >> BK_SHIFT], 1);
        atomicAdd(&h_d[dst[e0 + i] >> BK_SHIFT], 1);
    }
    __syncthreads();
    int cs = h_s[t], cd = h_d[t];
    for (int d = 1; d < MAXBUK; d <<= 1) {
        int us = (t >= d) ? h_s[t - d] : 0;
        int ud = (t >= d) ? h_d[t - d] : 0;
        __syncthreads();
        h_s[t] += us; h_d[t] += ud;
        __syncthreads();
    }
    int ex_s = h_s[t] - cs, ex_d = h_d[t] - cd;
    off_s[t] = ex_s; cur_s[t] = ex_s;
    off_d[t] = ex_d; cur_d[t] = ex_d;
    if (cs > 0) base_s[t] = atomicAdd(&gcur_src[t], cs);
    if (cd > 0) base_d[t] = atomicAdd(&gcur_dst[t], cd);
    __syncthreads();
    for (int i = t; i < ecnt; i += 512) {
        int e = e0 + i;
        int s = src[e], d = dst[e];
        int bs = s >> BK_SHIFT, bd = d >> BK_SHIFT;
        int ps = atomicAdd(&cur_s[bs], 1);
        st_s[ps] = ((uint32_t)(s & (BK_NODES - 1)) << SRC_SHIFT) | (uint32_t)e;
        bk_s[ps] = (unsigned short)bs;
        int pd = atomicAdd(&cur_d[bd], 1);
        st_d[pd] = ((uint32_t)(d & (BK_NODES - 1)) << DST_SHIFT) | (uint32_t)s;
        bk_d[pd] = (unsigned short)bd;
    }
    __syncthreads();
    for (int i = t; i < ecnt; i += 512) {
        int b1 = bk_s[i];
        bin_src[base_s[b1] + i - off_s[b1]] = st_s[i];
        int b2 = bk_d[i];
        bin_dst[base_d[b2] + i - off_d[b2]] = st_d[i];
    }
}

// ---------------------------------------------------------------------------
// Step 4: per-bucket fine counting sort, fully LDS-staged, coalesced output.
// blocks [0,nbuk) handle src side; [nbuk,2*nbuk) handle dst side. 256 threads.
// ---------------------------------------------------------------------------
__global__ void bucket_csr_kernel(const uint32_t* __restrict__ bin_src,
                                  const int* __restrict__ boff_src,
                                  int* __restrict__ src_edge, int* __restrict__ off_src,
                                  const uint32_t* __restrict__ bin_dst,
                                  const int* __restrict__ boff_dst,
                                  int* __restrict__ dst_srcid, int* __restrict__ off_dst,
                                  int nbuk, int N) {
    bool is_dst = blockIdx.x >= (unsigned)nbuk;
    int b = is_dst ? (blockIdx.x - nbuk) : blockIdx.x;
    const uint32_t* bin = is_dst ? bin_dst : bin_src;
    const int* boff = is_dst ? boff_dst : boff_src;
    int* outp = is_dst ? dst_srcid : src_edge;
    int* offo = is_dst ? off_dst : off_src;
    int shift = is_dst ? DST_SHIFT : SRC_SHIFT;
    uint32_t mask = (1u << shift) - 1;

    __shared__ int hist[BK_NODES];
    __shared__ int cursor[BK_NODES];
    __shared__ uint32_t stage[L2_CAP];

    int t = threadIdx.x;  // 256
    int base = boff[b];
    int cnt = boff[b + 1] - base;
    int n0 = b << BK_SHIFT;
    int NL = min(N - n0, BK_NODES);

    hist[t] = 0;
    __syncthreads();
    for (int i = t; i < cnt; i += 256) {
        atomicAdd(&hist[bin[base + i] >> shift], 1);
    }
    __syncthreads();
    int c = hist[t];
    for (int d = 1; d < BK_NODES; d <<= 1) {
        int u = (t >= d) ? hist[t - d] : 0;
        __syncthreads();
        hist[t] += u;
        __syncthreads();
    }
    int excl = hist[t] - c;
    cursor[t] = excl;
    if (t < NL) offo[n0 + t] = base + excl;
    __syncthreads();
    for (int i = t; i < cnt; i += 256) {
        uint32_t w = bin[base + i];
        int local = (int)(w >> shift);
        int pos = atomicAdd(&cursor[local], 1);
        uint32_t payload = w & mask;
        if (pos < L2_CAP) stage[pos] = payload;
        else outp[base + pos] = (int)payload;   // rare overflow path
    }
    __syncthreads();
    int lim = min(cnt, L2_CAP);
    for (int i = t; i < lim; i += 256) outp[base + i] = (int)stage[i];
}

// ---------------------------------------------------------------------------
// agg_ea[n] = sum over out-edges of edge_attr[e]
// ---------------------------------------------------------------------------
__global__ void ea_gather_kernel(const float* __restrict__ ea,
                                 const int* __restrict__ off_src,
                                 const int* __restrict__ src_edge,
                                 float* __restrict__ agg_ea, int N) {
    int wave = (blockIdx.x * blockDim.x + threadIdx.x) >> 6;
    int lane = threadIdx.x & 63;
    if (wave >= N) return;
    int beg = off_src[wave], end = off_src[wave + 1];
    int j = lane >> 5;
    int c = lane & 31;
    float acc = 0.0f;
    if (c < EDGE_CH) {
        for (int i = beg + j; i < end; i += 2) {
            int e = src_edge[i];
            acc += ea[(long)e * EDGE_CH + c];
        }
    }
    acc += __shfl_xor(acc, 32, 64);
    if (lane < EDGE_CH) agg_ea[(long)wave * EDGE_CH + lane] = acc;
}

// ---------------------------------------------------------------------------
// x0[n] = x[n] + agg_ea[n] @ we.T + outdeg(n) * be
// ---------------------------------------------------------------------------
__global__ void x0_update_kernel(const float* __restrict__ x,
                                 const float* __restrict__ agg_ea,
                                 const int* __restrict__ off_src,
                                 const float* __restrict__ we,
                                 const float* __restrict__ be,
                                 float* __restrict__ x0, int N) {
    __shared__ float s_we[IN_CH * EDGE_CH];
    __shared__ float s_be[IN_CH];
    for (int i = threadIdx.x; i < IN_CH * EDGE_CH; i += blockDim.x) s_we[i] = we[i];
    if (threadIdx.x < IN_CH) s_be[threadIdx.x] = be[threadIdx.x];
    __syncthreads();
    int n = blockIdx.x * blockDim.x + threadIdx.x;
    if (n >= N) return;
    float a[EDGE_CH];
#pragma unroll
    for (int k = 0; k < EDGE_CH; ++k) a[k] = agg_ea[(long)n * EDGE_CH + k];
    float cnt = (float)(off_src[n + 1] - off_src[n]);
#pragma unroll
    for (int o = 0; o < IN_CH; ++o) {
        float acc = x[(long)n * IN_CH + o] + cnt * s_be[o];
#pragma unroll
        for (int k = 0; k < EDGE_CH; ++k) acc += a[k] * s_we[o * EDGE_CH + k];
        x0[(long)n * IN_CH + o] = acc;
    }
}

// ---------------------------------------------------------------------------
// mean11: wave per node, 4 groups of 16 lanes
// ---------------------------------------------------------------------------
__global__ void agg11_kernel(const float* __restrict__ h,
                             const int* __restrict__ off_dst,
                             const int* __restrict__ srcid,
                             float* __restrict__ mean, int N) {
    int wave = (blockIdx.x * blockDim.x + threadIdx.x) >> 6;
    int lane = threadIdx.x & 63;
    if (wave >= N) return;
    int beg = off_dst[wave], end = off_dst[wave + 1];
    int j = lane >> 4;
    int c = lane & 15;
    float acc = 0.0f;
    if (c < IN_CH) {
        for (int i = beg + j; i < end; i += 4) {
            acc += h[(long)srcid[i] * IN_CH + c];
        }
    }
    acc += __shfl_xor(acc, 16, 64);
    acc += __shfl_xor(acc, 32, 64);
    if (lane < IN_CH) {
        float inv = 1.0f / fmaxf((float)(end - beg), 1.0f);
        mean[(long)wave * IN_CH + lane] = acc * inv;
    }
}

// ---------------------------------------------------------------------------
// mean64: wave per node, lane = channel
// ---------------------------------------------------------------------------
__global__ void agg64_kernel(const float* __restrict__ h,
                             const int* __restrict__ off_dst,
                             const int* __restrict__ srcid,
                             float* __restrict__ mean, int N) {
    int wave = (blockIdx.x * blockDim.x + threadIdx.x) >> 6;
    int lane = threadIdx.x & 63;
    if (wave >= N) return;
    int beg = off_dst[wave], end = off_dst[wave + 1];
    float a0 = 0.0f, a1 = 0.0f;
    int i = beg;
    for (; i + 1 < end; i += 2) {
        int s0 = srcid[i], s1 = srcid[i + 1];
        a0 += h[(long)s0 * HID + lane];
        a1 += h[(long)s1 * HID + lane];
    }
    if (i < end) a0 += h[(long)srcid[i] * HID + lane];
    float inv = 1.0f / fmaxf((float)(end - beg), 1.0f);
    mean[(long)wave * HID + lane] = (a0 + a1) * inv;
}

// ---------------------------------------------------------------------------
// h_out[n] = relu(mean[n] @ lw.T + lb + h_in[n] @ rw.T)
// ---------------------------------------------------------------------------
template <int CIN>
__global__ void update_kernel(const float* __restrict__ h_in,
                              const float* __restrict__ mean,
                              const float* __restrict__ lw,
                              const float* __restrict__ lb,
                              const float* __restrict__ rw,
                              float* __restrict__ h_out, int N) {
    __shared__ float s_lw[CIN][HID];
    __shared__ float s_rw[CIN][HID];
    __shared__ float s_lb[HID];
    __shared__ float s_hin[4][CIN];
    __shared__ float s_mean[4][CIN];
    for (int i = threadIdx.x; i < HID * CIN; i += blockDim.x) {
        int o = i / CIN, c = i % CIN;
        s_lw[c][o] = lw[i];
        s_rw[c][o] = rw[i];
    }
    if (threadIdx.x < HID) s_lb[threadIdx.x] = lb[threadIdx.x];
    __syncthreads();
    int sub = threadIdx.x >> 6, lane = threadIdx.x & 63;
    int groups = (N + 3) >> 2;
    for (int g = blockIdx.x; g < groups; g += gridDim.x) {
        int n = g * 4 + sub;
        bool valid = n < N;
        if (valid && lane < CIN) {
            s_hin[sub][lane] = h_in[(long)n * CIN + lane];
            s_mean[sub][lane] = mean[(long)n * CIN + lane];
        }
        __syncthreads();
        if (valid) {
            float acc = s_lb[lane];
#pragma unroll
            for (int c2 = 0; c2 < CIN; ++c2)
                acc += s_mean[sub][c2] * s_lw[c2][lane] + s_hin[sub][c2] * s_rw[c2][lane];
            h_out[(long)n * HID + lane] = fmaxf(acc, 0.0f);
        }
        __syncthreads();
    }
}

// ---------------------------------------------------------------------------
// Pooling over sorted batch
// ---------------------------------------------------------------------------
__global__ void pool_kernel(const float* __restrict__ h,
                            const int* __restrict__ batch,
                            float* __restrict__ psum,
                            float* __restrict__ pcnt,
                            int N, int chunk) {
    int lane = threadIdx.x;  // 64
    int n0 = blockIdx.x * chunk;
    int n1 = min(n0 + chunk, N);
    float acc = 0.0f, cnt = 0.0f;
    int cur = -1;
    for (int n = n0; n < n1; ++n) {
        int g = batch[n];
        if (g != cur) {
            if (cur >= 0) {
                atomicAdd(&psum[(long)cur * HID + lane], acc);
                if (lane == 0) atomicAdd(&pcnt[cur], cnt);
            }
            cur = g;
            acc = 0.0f;
            cnt = 0.0f;
        }
        acc += h[(long)n * HID + lane];
        cnt += 1.0f;
    }
    if (cur >= 0) {
        atomicAdd(&psum[(long)cur * HID + lane], acc);
        if (lane == 0) atomicAdd(&pcnt[cur], cnt);
    }
}

__global__ void final_kernel(const float* __restrict__ psum,
                             const float* __restrict__ pcnt,
                             const float* __restrict__ wf,
                             const float* __restrict__ bf,
                             float* __restrict__ out, int G) {
    int g = blockIdx.x * blockDim.x + threadIdx.x;
    if (g < G) {
        float inv = 1.0f / fmaxf(pcnt[g], 1.0f);
        float o0 = bf[0], o1 = bf[1];
#pragma unroll
        for (int c = 0; c < HID; ++c) {
            float p = psum[(long)g * HID + c] * inv;
            o0 += p * wf[c];
            o1 += p * wf[HID + c];
        }
        out[g * N_CLS + 0] = o0;
        out[g * N_CLS + 1] = o1;
    }
}

extern "C" void kernel_launch(void* const* d_in, const int* in_sizes, int n_in,
                              void* d_out, int out_size, void* d_ws, size_t ws_size,
                              hipStream_t stream) {
    const float* x         = (const float*)d_in[0];
    const float* edge_attr = (const float*)d_in[1];
    const int*   edge_idx  = (const int*)d_in[2];
    const int*   batch     = (const int*)d_in[3];
    const float* we  = (const float*)d_in[4];
    const float* be  = (const float*)d_in[5];
    const float* l1w = (const float*)d_in[6];
    const float* l1b = (const float*)d_in[7];
    const float* r1w = (const float*)d_in[8];
    const float* l2w = (const float*)d_in[9];
    const float* l2b = (const float*)d_in[10];
    const float* r2w = (const float*)d_in[11];
    const float* l3w = (const float*)d_in[12];
    const float* l3b = (const float*)d_in[13];
    const float* r3w = (const float*)d_in[14];
    const float* wf  = (const float*)d_in[15];
    const float* bf  = (const float*)d_in[16];

    const int E = in_sizes[2] / 2;
    const int N = in_sizes[3];
    const int* src = edge_idx;
    const int* dst = edge_idx + E;
    const int nbuk = (N + BK_NODES - 1) >> BK_SHIFT;   // 391

    // ---- workspace layout ----
    char* p = (char*)d_ws;
    int* off_src   = (int*)p;            p += (size_t)(N + 1) * 4;
    int* off_dst   = (int*)p;            p += (size_t)(N + 1) * 4;
    int* bc_src    = (int*)p;            p += (size_t)MAXBUK * 4;
    int* bc_dst    = (int*)p;            p += (size_t)MAXBUK * 4;
    int* boff_src  = (int*)p;            p += (size_t)(MAXBUK + 1) * 4;
    int* boff_dst  = (int*)p;            p += (size_t)(MAXBUK + 1) * 4;
    int* gcur_src  = (int*)p;            p += (size_t)MAXBUK * 4;
    int* gcur_dst  = (int*)p;            p += (size_t)MAXBUK * 4;
    int* src_edge  = (int*)p;            p += (size_t)E * 4;
    int* dst_srcid = (int*)p;            p += (size_t)E * 4;
    float* x0      = (float*)p;          p += (size_t)N * IN_CH * 4;
    float* tmpM    = (float*)p;          p += (size_t)N * HID * 4;
    float* bufA    = (float*)p;          p += (size_t)N * HID * 4;
    float* bufB    = (float*)p;          p += (size_t)N * HID * 4;
    float* psum    = (float*)p;          p += (size_t)N_GRAPHS * HID * 4;
    float* pcnt    = (float*)p;          p += (size_t)N_GRAPHS * 4;

    // bins alias bufA (dead during CSR build; 2*E ints == N*HID floats here)
    uint32_t* bin_src = (uint32_t*)bufA;
    uint32_t* bin_dst = bin_src + E;

    const int NW = (N + 3) / 4;

    // ---- CSR build (LDS-staged counting sort) ----
    hipMemsetAsync(bc_src, 0, (size_t)MAXBUK * 2 * 4, stream);   // bc_src + bc_dst adjacent
    prehist_kernel<<<512, 256, 0, stream>>>(src, dst, bc_src, bc_dst, E, nbuk);
    bucket_scan_kernel<<<1, MAXBUK, 0, stream>>>(bc_src, bc_dst, boff_src, boff_dst,
                                                 gcur_src, gcur_dst, off_src, off_dst,
                                                 nbuk, N, E);
    binscatter_kernel<<<(E + L1_CHUNK - 1) / L1_CHUNK, 512, 0, stream>>>(
        src, dst, gcur_src, gcur_dst, bin_src, bin_dst, E, nbuk);
    bucket_csr_kernel<<<2 * nbuk, 256, 0, stream>>>(
        bin_src, boff_src, src_edge, off_src,
        bin_dst, boff_dst, dst_srcid, off_dst, nbuk, N);

    // ---- edge correction ----
    ea_gather_kernel<<<NW, 256, 0, stream>>>(edge_attr, off_src, src_edge, tmpM, N);
    x0_update_kernel<<<(N + 255) / 256, 256, 0, stream>>>(x, tmpM, off_src, we, be, x0, N);

    // ---- layer 1 ----
    agg11_kernel<<<NW, 256, 0, stream>>>(x0, off_dst, dst_srcid, tmpM, N);
    update_kernel<IN_CH><<<2048, 256, 0, stream>>>(x0, tmpM, l1w, l1b, r1w, bufA, N);

    // ---- layer 2 ----
    agg64_kernel<<<NW, 256, 0, stream>>>(bufA, off_dst, dst_srcid, tmpM, N);
    update_kernel<HID><<<2048, 256, 0, stream>>>(bufA, tmpM, l2w, l2b, r2w, bufB, N);

    // ---- layer 3 ----
    agg64_kernel<<<NW, 256, 0, stream>>>(bufB, off_dst, dst_srcid, tmpM, N);
    update_kernel<HID><<<2048, 256, 0, stream>>>(bufB, tmpM, l3w, l3b, r3w, bufA, N);

    // ---- pool + classify ----
    hipMemsetAsync(psum, 0, (size_t)(N_GRAPHS * HID + N_GRAPHS) * 4, stream);
    {
        int pb = 256;
        int chunk = (N + pb - 1) / pb;
        pool_kernel<<<pb, 64, 0, stream>>>(bufA, batch, psum, pcnt, N, chunk);
    }
    final_kernel<<<(N_GRAPHS + 255) / 256, 256, 0, stream>>>(psum, pcnt, wf, bf,
                                                             (float*)d_out, N_GRAPHS);
}

// Round 4
// 1232.906 us; speedup vs baseline: 4.7152x; 1.2232x over previous
//
#include <hip/hip_runtime.h>
#include <stdint.h>

#define IN_CH 11
#define EDGE_CH 22
#define HID 64
#define N_CLS 2
#define N_GRAPHS 256

// Coarse buckets: 256 nodes per bucket (node >> 8). N=100000 -> 391 buckets.
#define BK_SHIFT 8
#define BK_NODES 256
#define MAXBUK 512          // padded power-of-2 for scans
#define L1_CHUNK 4096       // edges per binscatter block
#define L2_CAP 16384        // LDS staging entries in bucket_csr (64 KB)

// src-side pack: (local<<22)|edge_id   (edge_id < 2^22 = 4.19M)
// dst-side pack: (local<<17)|src_id    (src_id  < 2^17 = 131072)
#define SRC_SHIFT 22
#define DST_SHIFT 17

// ---------------------------------------------------------------------------
// Step 1: coarse bucket histogram (LDS-staged, one flush per block)
// ---------------------------------------------------------------------------
__global__ void prehist_kernel(const int* __restrict__ src, const int* __restrict__ dst,
                               int* __restrict__ bc_src, int* __restrict__ bc_dst,
                               int E, int nbuk) {
    __shared__ int h_s[MAXBUK], h_d[MAXBUK];
    int t = threadIdx.x;  // 256
    for (int i = t; i < MAXBUK; i += 256) { h_s[i] = 0; h_d[i] = 0; }
    __syncthreads();
    int per = (E + gridDim.x - 1) / gridDim.x;
    int lo = blockIdx.x * per, hi = min(E, lo + per);
    for (int i = lo + t; i < hi; i += 256) {
        atomicAdd(&h_s[src[i] >> BK_SHIFT], 1);
        atomicAdd(&h_d[dst[i] >> BK_SHIFT], 1);
    }
    __syncthreads();
    for (int i = t; i < nbuk; i += 256) {
        if (h_s[i]) atomicAdd(&bc_src[i], h_s[i]);
        if (h_d[i]) atomicAdd(&bc_dst[i], h_d[i]);
    }
}

// ---------------------------------------------------------------------------
// Step 2: scan bucket counts -> bucket base offsets (+ cursor copies).
// ---------------------------------------------------------------------------
__global__ void bucket_scan_kernel(const int* __restrict__ bc_src, const int* __restrict__ bc_dst,
                                   int* __restrict__ boff_src, int* __restrict__ boff_dst,
                                   int* __restrict__ gcur_src, int* __restrict__ gcur_dst,
                                   int* __restrict__ off_src, int* __restrict__ off_dst,
                                   int nbuk, int N, int E) {
    __shared__ int a[MAXBUK], b[MAXBUK];
    int t = threadIdx.x;  // 512
    int ca = (t < nbuk) ? bc_src[t] : 0;
    int cb = (t < nbuk) ? bc_dst[t] : 0;
    a[t] = ca; b[t] = cb;
    __syncthreads();
    for (int d = 1; d < MAXBUK; d <<= 1) {
        int ua = (t >= d) ? a[t - d] : 0;
        int ub = (t >= d) ? b[t - d] : 0;
        __syncthreads();
        a[t] += ua; b[t] += ub;
        __syncthreads();
    }
    if (t < nbuk) {
        int ea = a[t] - ca, eb = b[t] - cb;
        boff_src[t] = ea; gcur_src[t] = ea;
        boff_dst[t] = eb; gcur_dst[t] = eb;
    }
    if (t == 0) {
        boff_src[nbuk] = E; boff_dst[nbuk] = E;
        off_src[N] = E; off_dst[N] = E;
    }
}

// ---------------------------------------------------------------------------
// Step 3: bin edges by coarse bucket, LDS-sorted per 4096-edge chunk.
// ---------------------------------------------------------------------------
__global__ void binscatter_kernel(const int* __restrict__ src, const int* __restrict__ dst,
                                  int* __restrict__ gcur_src, int* __restrict__ gcur_dst,
                                  uint32_t* __restrict__ bin_src, uint32_t* __restrict__ bin_dst,
                                  int E, int nbuk) {
    __shared__ int h_s[MAXBUK], h_d[MAXBUK];
    __shared__ int off_s[MAXBUK], off_d[MAXBUK];
    __shared__ int cur_s[MAXBUK], cur_d[MAXBUK];
    __shared__ int base_s[MAXBUK], base_d[MAXBUK];
    __shared__ uint32_t st_s[L1_CHUNK], st_d[L1_CHUNK];
    __shared__ unsigned short bk_s[L1_CHUNK], bk_d[L1_CHUNK];

    int t = threadIdx.x;  // 512
    int e0 = blockIdx.x * L1_CHUNK;
    int ecnt = min(E - e0, L1_CHUNK);

    h_s[t] = 0; h_d[t] = 0;
    __syncthreads();
    for (int i = t; i < ecnt; i += 512) {
        atomicAdd(&h_s[src[e0 + i] >> BK_SHIFT], 1);
        atomicAdd(&h_d[dst[e0 + i] >> BK_SHIFT], 1);
    }
    __syncthreads();
    int cs = h_s[t], cd = h_d[t];
    for (int d = 1; d < MAXBUK; d <<= 1) {
        int us = (t >= d) ? h_s[t - d] : 0;
        int ud = (t >= d) ? h_d[t - d] : 0;
        __syncthreads();
        h_s[t] += us; h_d[t] += ud;
        __syncthreads();
    }
    int ex_s = h_s[t] - cs, ex_d = h_d[t] - cd;
    off_s[t] = ex_s; cur_s[t] = ex_s;
    off_d[t] = ex_d; cur_d[t] = ex_d;
    if (cs > 0) base_s[t] = atomicAdd(&gcur_src[t], cs);
    if (cd > 0) base_d[t] = atomicAdd(&gcur_dst[t], cd);
    __syncthreads();
    for (int i = t; i < ecnt; i += 512) {
        int e = e0 + i;
        int s = src[e], d = dst[e];
        int bs = s >> BK_SHIFT, bd = d >> BK_SHIFT;
        int ps = atomicAdd(&cur_s[bs], 1);
        st_s[ps] = ((uint32_t)(s & (BK_NODES - 1)) << SRC_SHIFT) | (uint32_t)e;
        bk_s[ps] = (unsigned short)bs;
        int pd = atomicAdd(&cur_d[bd], 1);
        st_d[pd] = ((uint32_t)(d & (BK_NODES - 1)) << DST_SHIFT) | (uint32_t)s;
        bk_d[pd] = (unsigned short)bd;
    }
    __syncthreads();
    for (int i = t; i < ecnt; i += 512) {
        int b1 = bk_s[i];
        bin_src[base_s[b1] + i - off_s[b1]] = st_s[i];
        int b2 = bk_d[i];
        bin_dst[base_d[b2] + i - off_d[b2]] = st_d[i];
    }
}

// ---------------------------------------------------------------------------
// Step 4: per-bucket fine counting sort, fully LDS-staged, coalesced output.
// ---------------------------------------------------------------------------
__global__ void bucket_csr_kernel(const uint32_t* __restrict__ bin_src,
                                  const int* __restrict__ boff_src,
                                  int* __restrict__ src_edge, int* __restrict__ off_src,
                                  const uint32_t* __restrict__ bin_dst,
                                  const int* __restrict__ boff_dst,
                                  int* __restrict__ dst_srcid, int* __restrict__ off_dst,
                                  int nbuk, int N) {
    bool is_dst = blockIdx.x >= (unsigned)nbuk;
    int b = is_dst ? (blockIdx.x - nbuk) : blockIdx.x;
    const uint32_t* bin = is_dst ? bin_dst : bin_src;
    const int* boff = is_dst ? boff_dst : boff_src;
    int* outp = is_dst ? dst_srcid : src_edge;
    int* offo = is_dst ? off_dst : off_src;
    int shift = is_dst ? DST_SHIFT : SRC_SHIFT;
    uint32_t mask = (1u << shift) - 1;

    __shared__ int hist[BK_NODES];
    __shared__ int cursor[BK_NODES];
    __shared__ uint32_t stage[L2_CAP];

    int t = threadIdx.x;  // 256
    int base = boff[b];
    int cnt = boff[b + 1] - base;
    int n0 = b << BK_SHIFT;
    int NL = min(N - n0, BK_NODES);

    hist[t] = 0;
    __syncthreads();
    for (int i = t; i < cnt; i += 256) {
        atomicAdd(&hist[bin[base + i] >> shift], 1);
    }
    __syncthreads();
    int c = hist[t];
    for (int d = 1; d < BK_NODES; d <<= 1) {
        int u = (t >= d) ? hist[t - d] : 0;
        __syncthreads();
        hist[t] += u;
        __syncthreads();
    }
    int excl = hist[t] - c;
    cursor[t] = excl;
    if (t < NL) offo[n0 + t] = base + excl;
    __syncthreads();
    for (int i = t; i < cnt; i += 256) {
        uint32_t w = bin[base + i];
        int local = (int)(w >> shift);
        int pos = atomicAdd(&cursor[local], 1);
        uint32_t payload = w & mask;
        if (pos < L2_CAP) stage[pos] = payload;
        else outp[base + pos] = (int)payload;   // rare overflow path
    }
    __syncthreads();
    int lim = min(cnt, L2_CAP);
    for (int i = t; i < lim; i += 256) outp[base + i] = (int)stage[i];
}

// ---------------------------------------------------------------------------
// agg_ea[n] = sum over out-edges of edge_attr[e]
// Deep-MLP version: 8 edge rows in flight per wave (2 groups x 4 accumulators)
// ---------------------------------------------------------------------------
__global__ void ea_gather_kernel(const float* __restrict__ ea,
                                 const int* __restrict__ off_src,
                                 const int* __restrict__ src_edge,
                                 float* __restrict__ agg_ea, int N) {
    int wave = (blockIdx.x * blockDim.x + threadIdx.x) >> 6;
    int lane = threadIdx.x & 63;
    if (wave >= N) return;
    int beg = off_src[wave], end = off_src[wave + 1];
    int j = lane >> 5;    // 0/1
    int c = lane & 31;
    float a0 = 0.0f, a1 = 0.0f, a2 = 0.0f, a3 = 0.0f;
    int i = beg;
    if (c < EDGE_CH) {
        for (; i + 7 < end; i += 8) {
            int e0 = src_edge[i + j];
            int e1 = src_edge[i + j + 2];
            int e2 = src_edge[i + j + 4];
            int e3 = src_edge[i + j + 6];
            float v0 = ea[(long)e0 * EDGE_CH + c];
            float v1 = ea[(long)e1 * EDGE_CH + c];
            float v2 = ea[(long)e2 * EDGE_CH + c];
            float v3 = ea[(long)e3 * EDGE_CH + c];
            a0 += v0; a1 += v1; a2 += v2; a3 += v3;
        }
        for (; i + j < end; i += 2) {
            a0 += ea[(long)src_edge[i + j] * EDGE_CH + c];
        }
    }
    float acc = (a0 + a1) + (a2 + a3);
    acc += __shfl_xor(acc, 32, 64);
    if (lane < EDGE_CH) agg_ea[(long)wave * EDGE_CH + lane] = acc;
}

// ---------------------------------------------------------------------------
// x0[n] = x[n] + agg_ea[n] @ we.T + outdeg(n) * be
// ---------------------------------------------------------------------------
__global__ void x0_update_kernel(const float* __restrict__ x,
                                 const float* __restrict__ agg_ea,
                                 const int* __restrict__ off_src,
                                 const float* __restrict__ we,
                                 const float* __restrict__ be,
                                 float* __restrict__ x0, int N) {
    __shared__ float s_we[IN_CH * EDGE_CH];
    __shared__ float s_be[IN_CH];
    for (int i = threadIdx.x; i < IN_CH * EDGE_CH; i += blockDim.x) s_we[i] = we[i];
    if (threadIdx.x < IN_CH) s_be[threadIdx.x] = be[threadIdx.x];
    __syncthreads();
    int n = blockIdx.x * blockDim.x + threadIdx.x;
    if (n >= N) return;
    float a[EDGE_CH];
#pragma unroll
    for (int k = 0; k < EDGE_CH; ++k) a[k] = agg_ea[(long)n * EDGE_CH + k];
    float cnt = (float)(off_src[n + 1] - off_src[n]);
#pragma unroll
    for (int o = 0; o < IN_CH; ++o) {
        float acc = x[(long)n * IN_CH + o] + cnt * s_be[o];
#pragma unroll
        for (int k = 0; k < EDGE_CH; ++k) acc += a[k] * s_we[o * EDGE_CH + k];
        x0[(long)n * IN_CH + o] = acc;
    }
}

// ---------------------------------------------------------------------------
// mean11: wave per node, 4 groups of 16 lanes, 2-deep unroll (8 rows in flight)
// ---------------------------------------------------------------------------
__global__ void agg11_kernel(const float* __restrict__ h,
                             const int* __restrict__ off_dst,
                             const int* __restrict__ srcid,
                             float* __restrict__ mean, int N) {
    int wave = (blockIdx.x * blockDim.x + threadIdx.x) >> 6;
    int lane = threadIdx.x & 63;
    if (wave >= N) return;
    int beg = off_dst[wave], end = off_dst[wave + 1];
    int j = lane >> 4;    // 0..3
    int c = lane & 15;
    float a0 = 0.0f, a1 = 0.0f;
    int i = beg;
    if (c < IN_CH) {
        for (; i + 7 < end; i += 8) {
            int s0 = srcid[i + j];
            int s1 = srcid[i + j + 4];
            float v0 = h[(long)s0 * IN_CH + c];
            float v1 = h[(long)s1 * IN_CH + c];
            a0 += v0; a1 += v1;
        }
        for (; i + j < end; i += 4) {
            a0 += h[(long)srcid[i + j] * IN_CH + c];
        }
    }
    float acc = a0 + a1;
    acc += __shfl_xor(acc, 16, 64);
    acc += __shfl_xor(acc, 32, 64);
    if (lane < IN_CH) {
        float inv = 1.0f / fmaxf((float)(end - beg), 1.0f);
        mean[(long)wave * IN_CH + lane] = acc * inv;
    }
}

// ---------------------------------------------------------------------------
// mean64: wave per node, lane = channel, 4-deep unroll (1 KB in flight/wave)
// ---------------------------------------------------------------------------
__global__ void agg64_kernel(const float* __restrict__ h,
                             const int* __restrict__ off_dst,
                             const int* __restrict__ srcid,
                             float* __restrict__ mean, int N) {
    int wave = (blockIdx.x * blockDim.x + threadIdx.x) >> 6;
    int lane = threadIdx.x & 63;
    if (wave >= N) return;
    int beg = off_dst[wave], end = off_dst[wave + 1];
    float a0 = 0.0f, a1 = 0.0f, a2 = 0.0f, a3 = 0.0f;
    int i = beg;
    for (; i + 3 < end; i += 4) {
        int s0 = srcid[i], s1 = srcid[i + 1], s2 = srcid[i + 2], s3 = srcid[i + 3];
        float v0 = h[(long)s0 * HID + lane];
        float v1 = h[(long)s1 * HID + lane];
        float v2 = h[(long)s2 * HID + lane];
        float v3 = h[(long)s3 * HID + lane];
        a0 += v0; a1 += v1; a2 += v2; a3 += v3;
    }
    for (; i < end; ++i) a0 += h[(long)srcid[i] * HID + lane];
    float inv = 1.0f / fmaxf((float)(end - beg), 1.0f);
    mean[(long)wave * HID + lane] = ((a0 + a1) + (a2 + a3)) * inv;
}

// ---------------------------------------------------------------------------
// h_out[n] = relu(mean[n] @ lw.T + lb + h_in[n] @ rw.T)
// ---------------------------------------------------------------------------
template <int CIN>
__global__ void update_kernel(const float* __restrict__ h_in,
                              const float* __restrict__ mean,
                              const float* __restrict__ lw,
                              const float* __restrict__ lb,
                              const float* __restrict__ rw,
                              float* __restrict__ h_out, int N) {
    __shared__ float s_lw[CIN][HID];
    __shared__ float s_rw[CIN][HID];
    __shared__ float s_lb[HID];
    __shared__ float s_hin[4][CIN];
    __shared__ float s_mean[4][CIN];
    for (int i = threadIdx.x; i < HID * CIN; i += blockDim.x) {
        int o = i / CIN, c = i % CIN;
        s_lw[c][o] = lw[i];
        s_rw[c][o] = rw[i];
    }
    if (threadIdx.x < HID) s_lb[threadIdx.x] = lb[threadIdx.x];
    __syncthreads();
    int sub = threadIdx.x >> 6, lane = threadIdx.x & 63;
    int groups = (N + 3) >> 2;
    for (int g = blockIdx.x; g < groups; g += gridDim.x) {
        int n = g * 4 + sub;
        bool valid = n < N;
        if (valid && lane < CIN) {
            s_hin[sub][lane] = h_in[(long)n * CIN + lane];
            s_mean[sub][lane] = mean[(long)n * CIN + lane];
        }
        __syncthreads();
        if (valid) {
            float acc = s_lb[lane];
#pragma unroll
            for (int c2 = 0; c2 < CIN; ++c2)
                acc += s_mean[sub][c2] * s_lw[c2][lane] + s_hin[sub][c2] * s_rw[c2][lane];
            h_out[(long)n * HID + lane] = fmaxf(acc, 0.0f);
        }
        __syncthreads();
    }
}

// ---------------------------------------------------------------------------
// Pooling over sorted batch
// ---------------------------------------------------------------------------
__global__ void pool_kernel(const float* __restrict__ h,
                            const int* __restrict__ batch,
                            float* __restrict__ psum,
                            float* __restrict__ pcnt,
                            int N, int chunk) {
    int lane = threadIdx.x;  // 64
    int n0 = blockIdx.x * chunk;
    int n1 = min(n0 + chunk, N);
    float acc = 0.0f, cnt = 0.0f;
    int cur = -1;
    for (int n = n0; n < n1; ++n) {
        int g = batch[n];
        if (g != cur) {
            if (cur >= 0) {
                atomicAdd(&psum[(long)cur * HID + lane], acc);
                if (lane == 0) atomicAdd(&pcnt[cur], cnt);
            }
            cur = g;
            acc = 0.0f;
            cnt = 0.0f;
        }
        acc += h[(long)n * HID + lane];
        cnt += 1.0f;
    }
    if (cur >= 0) {
        atomicAdd(&psum[(long)cur * HID + lane], acc);
        if (lane == 0) atomicAdd(&pcnt[cur], cnt);
    }
}

__global__ void final_kernel(const float* __restrict__ psum,
                             const float* __restrict__ pcnt,
                             const float* __restrict__ wf,
                             const float* __restrict__ bf,
                             float* __restrict__ out, int G) {
    int g = blockIdx.x * blockDim.x + threadIdx.x;
    if (g < G) {
        float inv = 1.0f / fmaxf(pcnt[g], 1.0f);
        float o0 = bf[0], o1 = bf[1];
#pragma unroll
        for (int c = 0; c < HID; ++c) {
            float p = psum[(long)g * HID + c] * inv;
            o0 += p * wf[c];
            o1 += p * wf[HID + c];
        }
        out[g * N_CLS + 0] = o0;
        out[g * N_CLS + 1] = o1;
    }
}

extern "C" void kernel_launch(void* const* d_in, const int* in_sizes, int n_in,
                              void* d_out, int out_size, void* d_ws, size_t ws_size,
                              hipStream_t stream) {
    const float* x         = (const float*)d_in[0];
    const float* edge_attr = (const float*)d_in[1];
    const int*   edge_idx  = (const int*)d_in[2];
    const int*   batch     = (const int*)d_in[3];
    const float* we  = (const float*)d_in[4];
    const float* be  = (const float*)d_in[5];
    const float* l1w = (const float*)d_in[6];
    const float* l1b = (const float*)d_in[7];
    const float* r1w = (const float*)d_in[8];
    const float* l2w = (const float*)d_in[9];
    const float* l2b = (const float*)d_in[10];
    const float* r2w = (const float*)d_in[11];
    const float* l3w = (const float*)d_in[12];
    const float* l3b = (const float*)d_in[13];
    const float* r3w = (const float*)d_in[14];
    const float* wf  = (const float*)d_in[15];
    const float* bf  = (const float*)d_in[16];

    const int E = in_sizes[2] / 2;
    const int N = in_sizes[3];
    const int* src = edge_idx;
    const int* dst = edge_idx + E;
    const int nbuk = (N + BK_NODES - 1) >> BK_SHIFT;   // 391

    // ---- workspace layout ----
    char* p = (char*)d_ws;
    int* off_src   = (int*)p;            p += (size_t)(N + 1) * 4;
    int* off_dst   = (int*)p;            p += (size_t)(N + 1) * 4;
    int* bc_src    = (int*)p;            p += (size_t)MAXBUK * 4;
    int* bc_dst    = (int*)p;            p += (size_t)MAXBUK * 4;
    int* boff_src  = (int*)p;            p += (size_t)(MAXBUK + 1) * 4;
    int* boff_dst  = (int*)p;            p += (size_t)(MAXBUK + 1) * 4;
    int* gcur_src  = (int*)p;            p += (size_t)MAXBUK * 4;
    int* gcur_dst  = (int*)p;            p += (size_t)MAXBUK * 4;
    int* src_edge  = (int*)p;            p += (size_t)E * 4;
    int* dst_srcid = (int*)p;            p += (size_t)E * 4;
    float* x0      = (float*)p;          p += (size_t)N * IN_CH * 4;
    float* tmpM    = (float*)p;          p += (size_t)N * HID * 4;
    float* bufA    = (float*)p;          p += (size_t)N * HID * 4;
    float* bufB    = (float*)p;          p += (size_t)N * HID * 4;
    float* psum    = (float*)p;          p += (size_t)N_GRAPHS * HID * 4;
    float* pcnt    = (float*)p;          p += (size_t)N_GRAPHS * 4;

    // bins alias bufA (dead during CSR build)
    uint32_t* bin_src = (uint32_t*)bufA;
    uint32_t* bin_dst = bin_src + E;

    const int NW = (N + 3) / 4;

    // ---- CSR build (LDS-staged counting sort) ----
    hipMemsetAsync(bc_src, 0, (size_t)MAXBUK * 2 * 4, stream);
    prehist_kernel<<<512, 256, 0, stream>>>(src, dst, bc_src, bc_dst, E, nbuk);
    bucket_scan_kernel<<<1, MAXBUK, 0, stream>>>(bc_src, bc_dst, boff_src, boff_dst,
                                                 gcur_src, gcur_dst, off_src, off_dst,
                                                 nbuk, N, E);
    binscatter_kernel<<<(E + L1_CHUNK - 1) / L1_CHUNK, 512, 0, stream>>>(
        src, dst, gcur_src, gcur_dst, bin_src, bin_dst, E, nbuk);
    bucket_csr_kernel<<<2 * nbuk, 256, 0, stream>>>(
        bin_src, boff_src, src_edge, off_src,
        bin_dst, boff_dst, dst_srcid, off_dst, nbuk, N);

    // ---- edge correction ----
    ea_gather_kernel<<<NW, 256, 0, stream>>>(edge_attr, off_src, src_edge, tmpM, N);
    x0_update_kernel<<<(N + 255) / 256, 256, 0, stream>>>(x, tmpM, off_src, we, be, x0, N);

    // ---- layer 1 ----
    agg11_kernel<<<NW, 256, 0, stream>>>(x0, off_dst, dst_srcid, tmpM, N);
    update_kernel<IN_CH><<<2048, 256, 0, stream>>>(x0, tmpM, l1w, l1b, r1w, bufA, N);

    // ---- layer 2 ----
    agg64_kernel<<<NW, 256, 0, stream>>>(bufA, off_dst, dst_srcid, tmpM, N);
    update_kernel<HID><<<2048, 256, 0, stream>>>(bufA, tmpM, l2w, l2b, r2w, bufB, N);

    // ---- layer 3 ----
    agg64_kernel<<<NW, 256, 0, stream>>>(bufB, off_dst, dst_srcid, tmpM, N);
    update_kernel<HID><<<2048, 256, 0, stream>>>(bufB, tmpM, l3w, l3b, r3w, bufA, N);

    // ---- pool + classify ----
    hipMemsetAsync(psum, 0, (size_t)(N_GRAPHS * HID + N_GRAPHS) * 4, stream);
    {
        int pb = 1024;
        int chunk = (N + pb - 1) / pb;
        pool_kernel<<<pb, 64, 0, stream>>>(bufA, batch, psum, pcnt, N, chunk);
    }
    final_kernel<<<(N_GRAPHS + 255) / 256, 256, 0, stream>>>(psum, pcnt, wf, bf,
                                                             (float*)d_out, N_GRAPHS);
}